// Round 16
// baseline (151.876 us; speedup 1.0000x reference)
//
#include <hip/hip_runtime.h>
#include <hip/hip_bf16.h>

// Problem constants
#define B_SZ 8
#define SEQ 512
#define D 768
#define D3 2304
#define NH 12
#define HD 64
#define NE 8
#define RANK 16
#define TT (B_SZ * SEQ)           // 4096 tokens
#define SCALING 2.0f              // ALPHA / RANK = 32/16
#define KE 2304                   // logical K, proj (bf16x3)
#define KQ 2560                   // logical K, QKV (bf16x3 + LoRA tail)
#define KA 1792                   // A2 phys width: [hi 768 | lo 768 | tail 256]
#define KB 1792                   // B2 phys width: [hi 768 | lo 768 | tail 256]
#define KAe 1536                  // Ae2 phys width: [hi | lo]
#define KWp 1536                  // Wpe phys width: [hi | lo]
#define NBH (B_SZ * NH)           // 96

typedef __attribute__((ext_vector_type(8))) short bh8;
typedef __attribute__((ext_vector_type(4))) float fx4;
typedef __attribute__((ext_vector_type(4))) unsigned ux4;

__device__ __forceinline__ unsigned short f2bf_rne(float x) {
    unsigned u = __float_as_uint(x);
    unsigned r = (u + 0x7FFFu + ((u >> 16) & 1u)) >> 16;
    return (unsigned short)r;
}
__device__ __forceinline__ float bf2f(unsigned short b) {
    return __uint_as_float(((unsigned)b) << 16);
}
__device__ __forceinline__ void load_lds16(const void* g, void* l) {
    __builtin_amdgcn_global_load_lds(
        (const __attribute__((address_space(1))) unsigned int*)g,
        (__attribute__((address_space(3))) unsigned int*)l,
        16, 0, 0);
}
// unpack 8 packed (hi,lo) u32 -> hi-bh8 and lo-bh8 (2-op mask/shift pairs)
__device__ __forceinline__ void unpack8(const unsigned* u, bh8& hi, bh8& lo) {
    unsigned* ph = (unsigned*)&hi;
    unsigned* pl = (unsigned*)&lo;
#pragma unroll
    for (int w = 0; w < 4; ++w) {
        ph[w] = (u[2 * w] & 0xffffu) | (u[2 * w + 1] << 16);
        pl[w] = (u[2 * w] >> 16) | (u[2 * w + 1] & 0xffff0000u);
    }
}

// hi/lo split conversion body: row r of in [M][768] -> out row [hi 768|lo 768]
template <int RS>
__device__ __forceinline__ void conv_body(
    const float* __restrict__ in, unsigned short* __restrict__ out, int gid)
{
    const int r = gid / 192;
    const int c4 = gid - r * 192;
    const float4 v = ((const float4*)(in + (size_t)r * D))[c4];
    ushort4 hi, lo;
    hi.x = f2bf_rne(v.x); hi.y = f2bf_rne(v.y);
    hi.z = f2bf_rne(v.z); hi.w = f2bf_rne(v.w);
    lo.x = f2bf_rne(v.x - bf2f(hi.x)); lo.y = f2bf_rne(v.y - bf2f(hi.y));
    lo.z = f2bf_rne(v.z - bf2f(hi.z)); lo.w = f2bf_rne(v.w - bf2f(hi.w));
    ushort4* row = (ushort4*)(out + (size_t)r * RS);
    row[c4] = hi;
    row[c4 + 192] = lo;
}

// ---------------------------------------------------------------------------
// Kernel W (fused uniform streaming prep):
//   [0,1728)     W_qkv -> B2 body (D3*192 items)
//   [1728,2304)  W_proj -> Wpe    (D*192)
//   [2304,3456)  B_lora -> B2 tail (D3*128)
// ---------------------------------------------------------------------------
__global__ __launch_bounds__(256) void k_wconv(
    const float* __restrict__ Wq, const float* __restrict__ Wp,
    const float* __restrict__ Bup,
    unsigned short* __restrict__ B2, unsigned short* __restrict__ Wpe)
{
    const int bid = blockIdx.x;
    const int tid = threadIdx.x;
    if (bid < 1728) {
        conv_body<KB>(Wq, B2, bid * 256 + tid);
    } else if (bid < 2304) {
        conv_body<KWp>(Wp, Wpe, (bid - 1728) * 256 + tid);
    } else {
        const int gid = (bid - 2304) * 256 + tid;
        const int n = gid >> 7;
        const int p = gid & 127;
        const int e = p >> 4, r = p & 15;
        const unsigned short h = f2bf_rne(Bup[((size_t)e * D3 + n) * RANK + r]);
        B2[(size_t)n * KB + 1536 + p] = h;
        B2[(size_t)n * KB + 1664 + p] = h;
    }
}

// ---------------------------------------------------------------------------
// Kernel 1: router (softmax gate, top-2) + LoRA down + x body conversion.
// ---------------------------------------------------------------------------
__global__ __launch_bounds__(64) void k_router(
    const float* __restrict__ x, const float* __restrict__ Wg,
    const float* __restrict__ bg, const float* __restrict__ A,
    unsigned short* __restrict__ A2)
{
    const int t = blockIdx.x;
    const int l = threadIdx.x;
    const float* xr = x + (size_t)t * D;

    float xv[12];
#pragma unroll
    for (int i = 0; i < 12; ++i) xv[i] = xr[l + 64 * i];

    unsigned short* arow = A2 + (size_t)t * KA;
#pragma unroll
    for (int i = 0; i < 12; ++i) {
        const unsigned short hi = f2bf_rne(xv[i]);
        const unsigned short lo = f2bf_rne(xv[i] - bf2f(hi));
        arow[i * 64 + l] = hi;
        arow[768 + i * 64 + l] = lo;
    }

    float p[NE];
#pragma unroll
    for (int e = 0; e < NE; ++e) {
        const float* w = Wg + (size_t)e * D;
        float s = 0.f;
#pragma unroll
        for (int i = 0; i < 12; ++i) s += xv[i] * w[l + 64 * i];
#pragma unroll
        for (int off = 32; off; off >>= 1) s += __shfl_xor(s, off);
        p[e] = s + bg[e];
    }
    float mx = p[0];
#pragma unroll
    for (int e = 1; e < NE; ++e) mx = fmaxf(mx, p[e]);
    float den = 0.f;
#pragma unroll
    for (int e = 0; e < NE; ++e) { p[e] = expf(p[e] - mx); den += p[e]; }
    int i0 = 0;
#pragma unroll
    for (int e = 1; e < NE; ++e) if (p[e] > p[i0]) i0 = e;
    int i1 = (i0 == 0) ? 1 : 0;
#pragma unroll
    for (int e = 0; e < NE; ++e) if (e != i1 && e != i0 && p[e] > p[i1]) i1 = e;
    const float w0 = p[i0] / den * SCALING;
    const float w1 = p[i1] / den * SCALING;

    unsigned short tv0 = 0, tv1 = 0, tv2 = 0, tv3 = 0;
    const int base = 4 * l;
#pragma unroll
    for (int j = 0; j < 2; ++j) {
        const int e = j ? i1 : i0;
        const float wj = j ? w1 : w0;
        const float* Ae = A + (size_t)e * RANK * D;
#pragma unroll
        for (int r = 0; r < RANK; ++r) {
            const float* a = Ae + (size_t)r * D;
            float s = 0.f;
#pragma unroll
            for (int i = 0; i < 12; ++i) s += xv[i] * a[l + 64 * i];
#pragma unroll
            for (int off = 32; off; off >>= 1) s += __shfl_xor(s, off);
            const float val = s * wj;
            const unsigned short hi = f2bf_rne(val);
            const unsigned short lo = f2bf_rne(val - bf2f(hi));
            const int ph = e * 16 + r;
            const int pl = ph + 128;
            tv0 = (base + 0 == ph) ? hi : ((base + 0 == pl) ? lo : tv0);
            tv1 = (base + 1 == ph) ? hi : ((base + 1 == pl) ? lo : tv1);
            tv2 = (base + 2 == ph) ? hi : ((base + 2 == pl) ? lo : tv2);
            tv3 = (base + 3 == ph) ? hi : ((base + 3 == pl) ? lo : tv3);
        }
    }
    ushort4 tq; tq.x = tv0; tq.y = tv1; tq.z = tv2; tq.w = tv3;
    *(ushort4*)(arow + 1536 + base) = tq;
}

// ---------------------------------------------------------------------------
// Kernel 2: bf16 MFMA GEMM over LOGICAL K (bf16x3 order via addr maps ka/kb).
// BK=64, XOR-swizzled LDS, XCD-swizzled grid.
// EPI=0: fp32 C + bias. EPI=1: fused QKV epilogue -> Qp/Kp packed (hi,lo)
// u32 [bh][s][64] (Q scaled 0.125; same coalescing as fp32) + bf16 Vt.
// ---------------------------------------------------------------------------
template <int FM, int FN, int EPI, int SA, int SB>
__global__ __launch_bounds__(256) void k_gemm_mfma(
    const unsigned short* __restrict__ Ae, const unsigned short* __restrict__ Be,
    const float* __restrict__ bias, float* __restrict__ C,
    int N, int K2,
    unsigned* __restrict__ Qp, unsigned* __restrict__ Kp,
    unsigned short* __restrict__ Vt)
{
    constexpr int BM = 2 * FM * 16;
    constexpr int BN = 2 * FN * 16;
    constexpr int ISS_A = BM / 32;
    constexpr int ISS_B = BN / 32;
    __shared__ __align__(16) unsigned short As[BM * 64];
    __shared__ __align__(16) unsigned short Bs[BN * 64];

    const int id = blockIdx.y * gridDim.x + blockIdx.x;
    const int cpx = (gridDim.x * gridDim.y) >> 3;
    const int swz = (id & 7) * cpx + (id >> 3);
    const int gx = swz % gridDim.x;
    const int gy = swz / gridDim.x;

    const int tid = threadIdx.x;
    const int lane = tid & 63;
    const int wv = tid >> 6;
    const int wr = wv >> 1, wc = wv & 1;
    const int m0 = gy * BM;
    const int n0 = gx * BN;

    fx4 acc[FM][FN] = {};

    const int arow = wv * 8 + (lane >> 3);
    const int acol = (((lane & 7) ^ (lane >> 3)) << 3);
    const int frow = lane & 15;

    for (int k0 = 0; k0 < K2; k0 += 64) {
        const int ka = (k0 < 768) ? k0 : k0 - 768;
        const int kb = (k0 < 1536) ? k0 : ((k0 < 2304) ? k0 - 1536 : k0 - 768);
#pragma unroll
        for (int i = 0; i < ISS_A; ++i)
            load_lds16(Ae + (size_t)(m0 + i * 32 + arow) * SA + ka + acol,
                       (char*)As + i * 4096 + wv * 1024);
#pragma unroll
        for (int i = 0; i < ISS_B; ++i)
            load_lds16(Be + (size_t)(n0 + i * 32 + arow) * SB + kb + acol,
                       (char*)Bs + i * 4096 + wv * 1024);
        __syncthreads();
#pragma unroll
        for (int kk = 0; kk < 2; ++kk) {
            const int un = ((((kk << 2) | (lane >> 4)) ^ (lane & 7)) << 3);
            bh8 afr[FM], bfr[FN];
#pragma unroll
            for (int i = 0; i < FM; ++i)
                afr[i] = *(const bh8*)&As[(wr * FM * 16 + i * 16 + frow) * 64 + un];
#pragma unroll
            for (int j = 0; j < FN; ++j)
                bfr[j] = *(const bh8*)&Bs[(wc * FN * 16 + j * 16 + frow) * 64 + un];
#pragma unroll
            for (int i = 0; i < FM; ++i)
#pragma unroll
                for (int j = 0; j < FN; ++j)
                    acc[i][j] = __builtin_amdgcn_mfma_f32_16x16x32_bf16(
                        afr[i], bfr[j], acc[i][j], 0, 0, 0);
        }
        __syncthreads();
    }

    const int col = lane & 15;
    const int rbase = (lane >> 4) * 4;

    if (EPI == 0) {
#pragma unroll
        for (int i = 0; i < FM; ++i) {
#pragma unroll
            for (int r = 0; r < 4; ++r) {
                const int m = m0 + wr * FM * 16 + i * 16 + rbase + r;
#pragma unroll
                for (int j = 0; j < FN; ++j) {
                    const int n = n0 + wc * FN * 16 + j * 16 + col;
                    C[(size_t)m * N + n] = acc[i][j][r] + bias[n];
                }
            }
        }
    } else {
        const int sec = n0 / D;   // 0=Q, 1=K, 2=V (768 % 96 == 0)
#pragma unroll
        for (int i = 0; i < FM; ++i) {
            const int mb = m0 + wr * FM * 16 + i * 16 + rbase;
#pragma unroll
            for (int j = 0; j < FN; ++j) {
                const int n = n0 + wc * FN * 16 + j * 16 + col;
                const int n2 = n - sec * D;
                const int h = n2 >> 6, d0 = n2 & 63;
                const float bi = bias[n];
                if (sec == 2) {
                    ushort4 vq;
                    vq.x = f2bf_rne(acc[i][j][0] + bi);
                    vq.y = f2bf_rne(acc[i][j][1] + bi);
                    vq.z = f2bf_rne(acc[i][j][2] + bi);
                    vq.w = f2bf_rne(acc[i][j][3] + bi);
                    const int b = mb >> 9, s = mb & 511;
                    *(ushort4*)(Vt + ((size_t)(b * NH + h) * HD + d0) * SEQ + s) = vq;
                } else {
                    unsigned* dst = (sec == 0) ? Qp : Kp;
#pragma unroll
                    for (int r = 0; r < 4; ++r) {
                        const int m = mb + r;
                        const int b = m >> 9, s = m & 511;
                        float c = acc[i][j][r] + bi;
                        if (sec == 0) c *= 0.125f;
                        const unsigned hi = f2bf_rne(c);
                        const unsigned lo = f2bf_rne(c - bf2f((unsigned short)hi));
                        dst[((size_t)(b * NH + h) * SEQ + s) * HD + d0] = hi | (lo << 16);
                    }
                }
            }
        }
    }
}

// ---------------------------------------------------------------------------
// Kernel 3: MFMA flash attention. 4 waves per (bh, 64-row Q-block).
// Q/K arrive as packed (hi,lo) u32 — unpack is 2-op mask/shift per word
// (replaces the 128-op split4 chains). Shfl-free softmax fast path + T13.
// ---------------------------------------------------------------------------
__global__ __launch_bounds__(256) void k_attn_mfma(
    const unsigned* __restrict__ Qp, const unsigned* __restrict__ Kp,
    const unsigned short* __restrict__ Vt, unsigned short* __restrict__ Ae2)
{
    __shared__ __align__(16) unsigned short Ks[64 * 136];
    __shared__ __align__(16) unsigned short Vs[64 * 72];
    __shared__ __align__(16) unsigned short Ps[4 * 16 * 72];

    const int bid = blockIdx.x;
    const int qb = bid & 7;
    const int bh = bid >> 3;
    const int b = bh / NH, h = bh - b * NH;
    const int tid = threadIdx.x;
    const int lane = tid & 63;
    const int wv = tid >> 6;
    const int lg = lane >> 4;
    const int lr = lane & 15;
    const int q0 = qb * 64 + wv * 16;

    bh8 qh0, qh1, ql0, ql1;
    {
        const unsigned* qrow = Qp + ((size_t)bh * SEQ + q0 + lr) * HD + lg * 8;
        unsigned u[16];
        *(ux4*)&u[0]  = ((const ux4*)qrow)[0];
        *(ux4*)&u[4]  = ((const ux4*)qrow)[1];
        *(ux4*)&u[8]  = ((const ux4*)(qrow + 32))[0];
        *(ux4*)&u[12] = ((const ux4*)(qrow + 32))[1];
        unpack8(&u[0], qh0, ql0);
        unpack8(&u[8], qh1, ql1);
    }
    bh8 qa[6] = {qh0, qh1, qh0, qh1, ql0, ql1};
    const int kcol[6] = {0, 32, 64, 96, 0, 32};

    fx4 o[4] = {};
    float m4[4], l4[4];
#pragma unroll
    for (int r = 0; r < 4; ++r) { m4[r] = -INFINITY; l4[r] = 0.f; }

    const int sr = tid >> 2, sc = tid & 3;
    ux4 ku0, ku1, ku2, ku3;
    bh8 vreg[2];
    {
        const unsigned* ksrc = Kp + ((size_t)bh * SEQ + sr) * HD + sc * 16;
        ku0 = ((const ux4*)ksrc)[0]; ku1 = ((const ux4*)ksrc)[1];
        ku2 = ((const ux4*)ksrc)[2]; ku3 = ((const ux4*)ksrc)[3];
        const unsigned short* vsrc = Vt + ((size_t)bh * HD + sr) * SEQ + sc * 16;
#pragma unroll
        for (int j = 0; j < 2; ++j) vreg[j] = *(const bh8*)(vsrc + j * 8);
    }

    for (int kt = 0; kt < 8; ++kt) {
        bh8 kh0, kh1, kl0, kl1;
        {
            unsigned u[16];
            *(ux4*)&u[0] = ku0; *(ux4*)&u[4] = ku1;
            *(ux4*)&u[8] = ku2; *(ux4*)&u[12] = ku3;
            unpack8(&u[0], kh0, kl0);
            unpack8(&u[8], kh1, kl1);
        }
        __syncthreads();
        {
            unsigned short* krow = &Ks[sr * 136 + sc * 16];
            *(bh8*)(krow)      = kh0; *(bh8*)(krow + 8)  = kh1;   // hi
            *(bh8*)(krow + 64) = kl0; *(bh8*)(krow + 72) = kl1;   // lo
        }
#pragma unroll
        for (int j = 0; j < 2; ++j)
            *(bh8*)&Vs[sr * 72 + sc * 16 + j * 8] = vreg[j];
        __syncthreads();
        if (kt < 7) {
            const int kv1 = (kt + 1) * 64;
            const unsigned* ksrc = Kp + ((size_t)bh * SEQ + kv1 + sr) * HD + sc * 16;
            ku0 = ((const ux4*)ksrc)[0]; ku1 = ((const ux4*)ksrc)[1];
            ku2 = ((const ux4*)ksrc)[2]; ku3 = ((const ux4*)ksrc)[3];
            const unsigned short* vsrc = Vt + ((size_t)bh * HD + sr) * SEQ + kv1 + sc * 16;
#pragma unroll
            for (int j = 0; j < 2; ++j) vreg[j] = *(const bh8*)(vsrc + j * 8);
        }

        fx4 sf[4] = {};
        __builtin_amdgcn_s_setprio(1);
#pragma unroll
        for (int kc = 0; kc < 6; ++kc) {
            bh8 kb[4];
#pragma unroll
            for (int j = 0; j < 4; ++j)
                kb[j] = *(const bh8*)&Ks[(j * 16 + lr) * 136 + kcol[kc] + lg * 8];
#pragma unroll
            for (int j = 0; j < 4; ++j)
                sf[j] = __builtin_amdgcn_mfma_f32_16x16x32_bf16(qa[kc], kb[j], sf[j], 0, 0, 0);
        }
        __builtin_amdgcn_s_setprio(0);

        // per-lane local max only (no shuffles on the fast path)
        float lmx[4];
#pragma unroll
        for (int r = 0; r < 4; ++r)
            lmx[r] = fmaxf(fmaxf(sf[0][r], sf[1][r]), fmaxf(sf[2][r], sf[3][r]));
        bool grow = false;
#pragma unroll
        for (int r = 0; r < 4; ++r) grow = grow || (lmx[r] > m4[r] + 8.f);
        if (__any(grow)) {
            float mxr[4];
#pragma unroll
            for (int r = 0; r < 4; ++r) mxr[r] = lmx[r];
#pragma unroll
            for (int off = 1; off < 16; off <<= 1)
#pragma unroll
                for (int r = 0; r < 4; ++r)
                    mxr[r] = fmaxf(mxr[r], __shfl_xor(mxr[r], off));
#pragma unroll
            for (int r = 0; r < 4; ++r) {
                const float mn = fmaxf(m4[r], mxr[r]);
                const float corr = __expf(m4[r] - mn);
                m4[r] = mn;
                l4[r] *= corr;
#pragma unroll
                for (int j = 0; j < 4; ++j) o[j][r] *= corr;
            }
        }

#pragma unroll
        for (int j = 0; j < 4; ++j)
#pragma unroll
            for (int r = 0; r < 4; ++r)
                sf[j][r] = __expf(sf[j][r] - m4[r]);
#pragma unroll
        for (int r = 0; r < 4; ++r)
            l4[r] += (sf[0][r] + sf[1][r]) + (sf[2][r] + sf[3][r]);

        unsigned short* pw = Ps + wv * (16 * 72);
#pragma unroll
        for (int j = 0; j < 4; ++j)
#pragma unroll
            for (int r = 0; r < 4; ++r)
                pw[(lg * 4 + r) * 72 + j * 16 + lr] = f2bf_rne(sf[j][r]);

        __builtin_amdgcn_s_setprio(1);
#pragma unroll
        for (int kc = 0; kc < 2; ++kc) {
            bh8 pa = *(const bh8*)&pw[lr * 72 + kc * 32 + lg * 8];
            bh8 vb[4];
#pragma unroll
            for (int j = 0; j < 4; ++j)
                vb[j] = *(const bh8*)&Vs[(j * 16 + lr) * 72 + kc * 32 + lg * 8];
#pragma unroll
            for (int j = 0; j < 4; ++j)
                o[j] = __builtin_amdgcn_mfma_f32_16x16x32_bf16(pa, vb[j], o[j], 0, 0, 0);
        }
        __builtin_amdgcn_s_setprio(0);
    }

    // single deferred 16-lane l reduction
#pragma unroll
    for (int off = 1; off < 16; off <<= 1)
#pragma unroll
        for (int r = 0; r < 4; ++r)
            l4[r] += __shfl_xor(l4[r], off);

    float inv[4];
#pragma unroll
    for (int r = 0; r < 4; ++r) inv[r] = 1.f / l4[r];
    const int trow = b * SEQ + q0 + lg * 4;
#pragma unroll
    for (int r = 0; r < 4; ++r) {
        unsigned short* row = Ae2 + (size_t)(trow + r) * KAe;
#pragma unroll
        for (int j = 0; j < 4; ++j) {
            const float v = o[j][r] * inv[r];
            const unsigned short hi = f2bf_rne(v);
            const unsigned short lo = f2bf_rne(v - bf2f(hi));
            const int c = h * HD + j * 16 + lr;
            row[c] = hi; row[768 + c] = lo;
        }
    }
}

// ---------------------------------------------------------------------------
extern "C" void kernel_launch(void* const* d_in, const int* in_sizes, int n_in,
                              void* d_out, int out_size, void* d_ws, size_t ws_size,
                              hipStream_t stream)
{
    const float* x      = (const float*)d_in[0];
    const float* W_qkv  = (const float*)d_in[1];
    const float* b_qkv  = (const float*)d_in[2];
    const float* W_gate = (const float*)d_in[3];
    const float* b_gate = (const float*)d_in[4];
    const float* A      = (const float*)d_in[5];
    const float* B_lora = (const float*)d_in[6];
    const float* W_proj = (const float*)d_in[7];
    const float* b_proj = (const float*)d_in[8];
    float* out = (float*)d_out;

    // workspace (~57 MB). Ae2 (TTxKAe) aliases A2 (TTxKA) — disjoint lifetimes.
    unsigned short* A2  = (unsigned short*)d_ws;        // TT x KA
    unsigned short* B2  = A2 + (size_t)TT * KA;         // D3 x KB
    unsigned* Qp        = (unsigned*)(B2 + (size_t)D3 * KB);  // NBH x 512 x 64 u32
    unsigned* Kp        = Qp + (size_t)NBH * SEQ * HD;        // NBH x 512 x 64 u32
    unsigned short* Vt  = (unsigned short*)(Kp + (size_t)NBH * SEQ * HD); // NBH x 64 x 512
    unsigned short* Wpe = Vt + (size_t)NBH * HD * SEQ;  // D x KWp
    unsigned short* Ae2 = A2;                           // TT x KAe (attn output)

    // 1. prep: router (+x conversion from registers) + uniform W streams
    k_router<<<TT, 64, 0, stream>>>(x, W_gate, b_gate, A, A2);
    k_wconv<<<3456, 256, 0, stream>>>(W_qkv, W_proj, B_lora, B2, Wpe);

    // 2. QKV GEMM (logical K=2560 bf16x3+LoRA over dedup'd phys storage)
    //    128x96 tiles -> 24x32 = 768 blocks = exactly 3/CU
    {
        dim3 grid(D3 / 96, TT / 128);
        k_gemm_mfma<4, 3, 1, KA, KB><<<grid, 256, 0, stream>>>(
            A2, B2, b_qkv, nullptr, D3, KQ, Qp, Kp, Vt);
    }

    // 3. MFMA flash attention -> Ae2 (phys [hi|lo], proj-ready)
    k_attn_mfma<<<NBH * 8, 256, 0, stream>>>(Qp, Kp, Vt, Ae2);

    // 4. output projection: 64x96 tiles -> 8x64 = 512 blocks = exactly 2/CU
    {
        dim3 grid(D / 96, TT / 64);
        k_gemm_mfma<2, 3, 0, KAe, KWp><<<grid, 256, 0, stream>>>(
            Ae2, Wpe, b_proj, out, D, KE, nullptr, nullptr, nullptr);
    }
}

// Round 17
// 146.477 us; speedup vs baseline: 1.0369x; 1.0369x over previous
//
#include <hip/hip_runtime.h>
#include <hip/hip_bf16.h>

// Problem constants
#define B_SZ 8
#define SEQ 512
#define D 768
#define D3 2304
#define NH 12
#define HD 64
#define NE 8
#define RANK 16
#define TT (B_SZ * SEQ)           // 4096 tokens
#define SCALING 2.0f              // ALPHA / RANK = 32/16
#define KE 2304                   // logical K, proj (bf16x3)
#define KQ 2560                   // logical K, QKV (bf16x3 + LoRA tail)
#define KA 1792                   // A2 phys width: [hi 768 | lo 768 | tail 256]
#define KB 1792                   // B2 phys width: [hi 768 | lo 768 | tail 256]
#define KAe 1536                  // Ae2 phys width: [hi | lo]
#define KWp 1536                  // Wpe phys width: [hi | lo]
#define NBH (B_SZ * NH)           // 96

typedef __attribute__((ext_vector_type(8))) short bh8;
typedef __attribute__((ext_vector_type(4))) float fx4;
typedef __attribute__((ext_vector_type(4))) unsigned ux4;

__device__ __forceinline__ unsigned short f2bf_rne(float x) {
    unsigned u = __float_as_uint(x);
    unsigned r = (u + 0x7FFFu + ((u >> 16) & 1u)) >> 16;
    return (unsigned short)r;
}
__device__ __forceinline__ float bf2f(unsigned short b) {
    return __uint_as_float(((unsigned)b) << 16);
}
__device__ __forceinline__ void load_lds16(const void* g, void* l) {
    __builtin_amdgcn_global_load_lds(
        (const __attribute__((address_space(1))) unsigned int*)g,
        (__attribute__((address_space(3))) unsigned int*)l,
        16, 0, 0);
}
// unpack 8 packed (hi,lo) u32 -> hi-bh8 and lo-bh8 (2-op mask/shift pairs)
__device__ __forceinline__ void unpack8(const unsigned* u, bh8& hi, bh8& lo) {
    unsigned* ph = (unsigned*)&hi;
    unsigned* pl = (unsigned*)&lo;
#pragma unroll
    for (int w = 0; w < 4; ++w) {
        ph[w] = (u[2 * w] & 0xffffu) | (u[2 * w + 1] << 16);
        pl[w] = (u[2 * w] >> 16) | (u[2 * w + 1] & 0xffff0000u);
    }
}

// hi/lo split conversion body: row r of in [M][768] -> out row [hi 768|lo 768]
template <int RS>
__device__ __forceinline__ void conv_body(
    const float* __restrict__ in, unsigned short* __restrict__ out, int gid)
{
    const int r = gid / 192;
    const int c4 = gid - r * 192;
    const float4 v = ((const float4*)(in + (size_t)r * D))[c4];
    ushort4 hi, lo;
    hi.x = f2bf_rne(v.x); hi.y = f2bf_rne(v.y);
    hi.z = f2bf_rne(v.z); hi.w = f2bf_rne(v.w);
    lo.x = f2bf_rne(v.x - bf2f(hi.x)); lo.y = f2bf_rne(v.y - bf2f(hi.y));
    lo.z = f2bf_rne(v.z - bf2f(hi.z)); lo.w = f2bf_rne(v.w - bf2f(hi.w));
    ushort4* row = (ushort4*)(out + (size_t)r * RS);
    row[c4] = hi;
    row[c4 + 192] = lo;
}

// ---------------------------------------------------------------------------
// Kernel W (fused uniform streaming prep):
//   [0,1728)     W_qkv -> B2 body (D3*192 items)
//   [1728,2304)  W_proj -> Wpe    (D*192)
//   [2304,3456)  B_lora -> B2 tail (D3*128)
// ---------------------------------------------------------------------------
__global__ __launch_bounds__(256) void k_wconv(
    const float* __restrict__ Wq, const float* __restrict__ Wp,
    const float* __restrict__ Bup,
    unsigned short* __restrict__ B2, unsigned short* __restrict__ Wpe)
{
    const int bid = blockIdx.x;
    const int tid = threadIdx.x;
    if (bid < 1728) {
        conv_body<KB>(Wq, B2, bid * 256 + tid);
    } else if (bid < 2304) {
        conv_body<KWp>(Wp, Wpe, (bid - 1728) * 256 + tid);
    } else {
        const int gid = (bid - 2304) * 256 + tid;
        const int n = gid >> 7;
        const int p = gid & 127;
        const int e = p >> 4, r = p & 15;
        const unsigned short h = f2bf_rne(Bup[((size_t)e * D3 + n) * RANK + r]);
        B2[(size_t)n * KB + 1536 + p] = h;
        B2[(size_t)n * KB + 1664 + p] = h;
    }
}

// ---------------------------------------------------------------------------
// Kernel 1: router (softmax gate, top-2) + LoRA down + x body conversion.
// ---------------------------------------------------------------------------
__global__ __launch_bounds__(64) void k_router(
    const float* __restrict__ x, const float* __restrict__ Wg,
    const float* __restrict__ bg, const float* __restrict__ A,
    unsigned short* __restrict__ A2)
{
    const int t = blockIdx.x;
    const int l = threadIdx.x;
    const float* xr = x + (size_t)t * D;

    float xv[12];
#pragma unroll
    for (int i = 0; i < 12; ++i) xv[i] = xr[l + 64 * i];

    unsigned short* arow = A2 + (size_t)t * KA;
#pragma unroll
    for (int i = 0; i < 12; ++i) {
        const unsigned short hi = f2bf_rne(xv[i]);
        const unsigned short lo = f2bf_rne(xv[i] - bf2f(hi));
        arow[i * 64 + l] = hi;
        arow[768 + i * 64 + l] = lo;
    }

    float p[NE];
#pragma unroll
    for (int e = 0; e < NE; ++e) {
        const float* w = Wg + (size_t)e * D;
        float s = 0.f;
#pragma unroll
        for (int i = 0; i < 12; ++i) s += xv[i] * w[l + 64 * i];
#pragma unroll
        for (int off = 32; off; off >>= 1) s += __shfl_xor(s, off);
        p[e] = s + bg[e];
    }
    float mx = p[0];
#pragma unroll
    for (int e = 1; e < NE; ++e) mx = fmaxf(mx, p[e]);
    float den = 0.f;
#pragma unroll
    for (int e = 0; e < NE; ++e) { p[e] = expf(p[e] - mx); den += p[e]; }
    int i0 = 0;
#pragma unroll
    for (int e = 1; e < NE; ++e) if (p[e] > p[i0]) i0 = e;
    int i1 = (i0 == 0) ? 1 : 0;
#pragma unroll
    for (int e = 0; e < NE; ++e) if (e != i1 && e != i0 && p[e] > p[i1]) i1 = e;
    const float w0 = p[i0] / den * SCALING;
    const float w1 = p[i1] / den * SCALING;

    unsigned short tv0 = 0, tv1 = 0, tv2 = 0, tv3 = 0;
    const int base = 4 * l;
#pragma unroll
    for (int j = 0; j < 2; ++j) {
        const int e = j ? i1 : i0;
        const float wj = j ? w1 : w0;
        const float* Ae = A + (size_t)e * RANK * D;
#pragma unroll
        for (int r = 0; r < RANK; ++r) {
            const float* a = Ae + (size_t)r * D;
            float s = 0.f;
#pragma unroll
            for (int i = 0; i < 12; ++i) s += xv[i] * a[l + 64 * i];
#pragma unroll
            for (int off = 32; off; off >>= 1) s += __shfl_xor(s, off);
            const float val = s * wj;
            const unsigned short hi = f2bf_rne(val);
            const unsigned short lo = f2bf_rne(val - bf2f(hi));
            const int ph = e * 16 + r;
            const int pl = ph + 128;
            tv0 = (base + 0 == ph) ? hi : ((base + 0 == pl) ? lo : tv0);
            tv1 = (base + 1 == ph) ? hi : ((base + 1 == pl) ? lo : tv1);
            tv2 = (base + 2 == ph) ? hi : ((base + 2 == pl) ? lo : tv2);
            tv3 = (base + 3 == ph) ? hi : ((base + 3 == pl) ? lo : tv3);
        }
    }
    ushort4 tq; tq.x = tv0; tq.y = tv1; tq.z = tv2; tq.w = tv3;
    *(ushort4*)(arow + 1536 + base) = tq;
}

// ---------------------------------------------------------------------------
// Kernel 2: bf16 MFMA GEMM over LOGICAL K (bf16x3 order via addr maps ka/kb).
// BK=64, XOR-swizzled LDS, XCD-swizzled grid.
// EPI=0: fp32 C + bias. EPI=1: fused QKV epilogue -> Qp/Kp packed (hi,lo)
// u32 [bh][s][64] (Q scaled 0.125) + bf16 Vt.
// ---------------------------------------------------------------------------
template <int FM, int FN, int EPI, int SA, int SB>
__global__ __launch_bounds__(256) void k_gemm_mfma(
    const unsigned short* __restrict__ Ae, const unsigned short* __restrict__ Be,
    const float* __restrict__ bias, float* __restrict__ C,
    int N, int K2,
    unsigned* __restrict__ Qp, unsigned* __restrict__ Kp,
    unsigned short* __restrict__ Vt)
{
    constexpr int BM = 2 * FM * 16;
    constexpr int BN = 2 * FN * 16;
    constexpr int ISS_A = BM / 32;
    constexpr int ISS_B = BN / 32;
    __shared__ __align__(16) unsigned short As[BM * 64];
    __shared__ __align__(16) unsigned short Bs[BN * 64];

    const int id = blockIdx.y * gridDim.x + blockIdx.x;
    const int cpx = (gridDim.x * gridDim.y) >> 3;
    const int swz = (id & 7) * cpx + (id >> 3);
    const int gx = swz % gridDim.x;
    const int gy = swz / gridDim.x;

    const int tid = threadIdx.x;
    const int lane = tid & 63;
    const int wv = tid >> 6;
    const int wr = wv >> 1, wc = wv & 1;
    const int m0 = gy * BM;
    const int n0 = gx * BN;

    fx4 acc[FM][FN] = {};

    const int arow = wv * 8 + (lane >> 3);
    const int acol = (((lane & 7) ^ (lane >> 3)) << 3);
    const int frow = lane & 15;

    for (int k0 = 0; k0 < K2; k0 += 64) {
        const int ka = (k0 < 768) ? k0 : k0 - 768;
        const int kb = (k0 < 1536) ? k0 : ((k0 < 2304) ? k0 - 1536 : k0 - 768);
#pragma unroll
        for (int i = 0; i < ISS_A; ++i)
            load_lds16(Ae + (size_t)(m0 + i * 32 + arow) * SA + ka + acol,
                       (char*)As + i * 4096 + wv * 1024);
#pragma unroll
        for (int i = 0; i < ISS_B; ++i)
            load_lds16(Be + (size_t)(n0 + i * 32 + arow) * SB + kb + acol,
                       (char*)Bs + i * 4096 + wv * 1024);
        __syncthreads();
#pragma unroll
        for (int kk = 0; kk < 2; ++kk) {
            const int un = ((((kk << 2) | (lane >> 4)) ^ (lane & 7)) << 3);
            bh8 afr[FM], bfr[FN];
#pragma unroll
            for (int i = 0; i < FM; ++i)
                afr[i] = *(const bh8*)&As[(wr * FM * 16 + i * 16 + frow) * 64 + un];
#pragma unroll
            for (int j = 0; j < FN; ++j)
                bfr[j] = *(const bh8*)&Bs[(wc * FN * 16 + j * 16 + frow) * 64 + un];
#pragma unroll
            for (int i = 0; i < FM; ++i)
#pragma unroll
                for (int j = 0; j < FN; ++j)
                    acc[i][j] = __builtin_amdgcn_mfma_f32_16x16x32_bf16(
                        afr[i], bfr[j], acc[i][j], 0, 0, 0);
        }
        __syncthreads();
    }

    const int col = lane & 15;
    const int rbase = (lane >> 4) * 4;

    if (EPI == 0) {
#pragma unroll
        for (int i = 0; i < FM; ++i) {
#pragma unroll
            for (int r = 0; r < 4; ++r) {
                const int m = m0 + wr * FM * 16 + i * 16 + rbase + r;
#pragma unroll
                for (int j = 0; j < FN; ++j) {
                    const int n = n0 + wc * FN * 16 + j * 16 + col;
                    C[(size_t)m * N + n] = acc[i][j][r] + bias[n];
                }
            }
        }
    } else {
        const int sec = n0 / D;   // 0=Q, 1=K, 2=V (768 % 96 == 0)
#pragma unroll
        for (int i = 0; i < FM; ++i) {
            const int mb = m0 + wr * FM * 16 + i * 16 + rbase;
#pragma unroll
            for (int j = 0; j < FN; ++j) {
                const int n = n0 + wc * FN * 16 + j * 16 + col;
                const int n2 = n - sec * D;
                const int h = n2 >> 6, d0 = n2 & 63;
                const float bi = bias[n];
                if (sec == 2) {
                    ushort4 vq;
                    vq.x = f2bf_rne(acc[i][j][0] + bi);
                    vq.y = f2bf_rne(acc[i][j][1] + bi);
                    vq.z = f2bf_rne(acc[i][j][2] + bi);
                    vq.w = f2bf_rne(acc[i][j][3] + bi);
                    const int b = mb >> 9, s = mb & 511;
                    *(ushort4*)(Vt + ((size_t)(b * NH + h) * HD + d0) * SEQ + s) = vq;
                } else {
                    unsigned* dst = (sec == 0) ? Qp : Kp;
#pragma unroll
                    for (int r = 0; r < 4; ++r) {
                        const int m = mb + r;
                        const int b = m >> 9, s = m & 511;
                        float c = acc[i][j][r] + bi;
                        if (sec == 0) c *= 0.125f;
                        const unsigned hi = f2bf_rne(c);
                        const unsigned lo = f2bf_rne(c - bf2f((unsigned short)hi));
                        dst[((size_t)(b * NH + h) * SEQ + s) * HD + d0] = hi | (lo << 16);
                    }
                }
            }
        }
    }
}

// ---------------------------------------------------------------------------
// Kernel 3: MFMA flash attention. 4 waves per (bh, 64-row Q-block).
// THIS ROUND: bh-locality block swizzle — bh = bid % 96, qb = bid / 96, so
// all 8 q-blocks of one bh share blockIdx ≡ bh (mod 8) -> same XCD ->
// K/V (~195 KB/bh; 12 bh x 2.3 MB per XCD fits 4 MB L2) fetched from HBM
// once and re-served 7x from local L2 (T1 mechanism applied to attention).
// ---------------------------------------------------------------------------
__global__ __launch_bounds__(256) void k_attn_mfma(
    const unsigned* __restrict__ Qp, const unsigned* __restrict__ Kp,
    const unsigned short* __restrict__ Vt, unsigned short* __restrict__ Ae2)
{
    __shared__ __align__(16) unsigned short Ks[64 * 136];
    __shared__ __align__(16) unsigned short Vs[64 * 72];
    __shared__ __align__(16) unsigned short Ps[4 * 16 * 72];

    const int bid = blockIdx.x;
    const int bh = bid % NBH;         // bh-locality swizzle (96 % 8 == 0)
    const int qb = bid / NBH;
    const int b = bh / NH, h = bh - b * NH;
    const int tid = threadIdx.x;
    const int lane = tid & 63;
    const int wv = tid >> 6;
    const int lg = lane >> 4;
    const int lr = lane & 15;
    const int q0 = qb * 64 + wv * 16;

    bh8 qh0, qh1, ql0, ql1;
    {
        const unsigned* qrow = Qp + ((size_t)bh * SEQ + q0 + lr) * HD + lg * 8;
        unsigned u[16];
        *(ux4*)&u[0]  = ((const ux4*)qrow)[0];
        *(ux4*)&u[4]  = ((const ux4*)qrow)[1];
        *(ux4*)&u[8]  = ((const ux4*)(qrow + 32))[0];
        *(ux4*)&u[12] = ((const ux4*)(qrow + 32))[1];
        unpack8(&u[0], qh0, ql0);
        unpack8(&u[8], qh1, ql1);
    }
    bh8 qa[6] = {qh0, qh1, qh0, qh1, ql0, ql1};
    const int kcol[6] = {0, 32, 64, 96, 0, 32};

    fx4 o[4] = {};
    float m4[4], l4[4];
#pragma unroll
    for (int r = 0; r < 4; ++r) { m4[r] = -INFINITY; l4[r] = 0.f; }

    const int sr = tid >> 2, sc = tid & 3;
    ux4 ku0, ku1, ku2, ku3;
    bh8 vreg[2];
    {
        const unsigned* ksrc = Kp + ((size_t)bh * SEQ + sr) * HD + sc * 16;
        ku0 = ((const ux4*)ksrc)[0]; ku1 = ((const ux4*)ksrc)[1];
        ku2 = ((const ux4*)ksrc)[2]; ku3 = ((const ux4*)ksrc)[3];
        const unsigned short* vsrc = Vt + ((size_t)bh * HD + sr) * SEQ + sc * 16;
#pragma unroll
        for (int j = 0; j < 2; ++j) vreg[j] = *(const bh8*)(vsrc + j * 8);
    }

    for (int kt = 0; kt < 8; ++kt) {
        bh8 kh0, kh1, kl0, kl1;
        {
            unsigned u[16];
            *(ux4*)&u[0] = ku0; *(ux4*)&u[4] = ku1;
            *(ux4*)&u[8] = ku2; *(ux4*)&u[12] = ku3;
            unpack8(&u[0], kh0, kl0);
            unpack8(&u[8], kh1, kl1);
        }
        __syncthreads();
        {
            unsigned short* krow = &Ks[sr * 136 + sc * 16];
            *(bh8*)(krow)      = kh0; *(bh8*)(krow + 8)  = kh1;   // hi
            *(bh8*)(krow + 64) = kl0; *(bh8*)(krow + 72) = kl1;   // lo
        }
#pragma unroll
        for (int j = 0; j < 2; ++j)
            *(bh8*)&Vs[sr * 72 + sc * 16 + j * 8] = vreg[j];
        __syncthreads();
        if (kt < 7) {
            const int kv1 = (kt + 1) * 64;
            const unsigned* ksrc = Kp + ((size_t)bh * SEQ + kv1 + sr) * HD + sc * 16;
            ku0 = ((const ux4*)ksrc)[0]; ku1 = ((const ux4*)ksrc)[1];
            ku2 = ((const ux4*)ksrc)[2]; ku3 = ((const ux4*)ksrc)[3];
            const unsigned short* vsrc = Vt + ((size_t)bh * HD + sr) * SEQ + kv1 + sc * 16;
#pragma unroll
            for (int j = 0; j < 2; ++j) vreg[j] = *(const bh8*)(vsrc + j * 8);
        }

        fx4 sf[4] = {};
        __builtin_amdgcn_s_setprio(1);
#pragma unroll
        for (int kc = 0; kc < 6; ++kc) {
            bh8 kb[4];
#pragma unroll
            for (int j = 0; j < 4; ++j)
                kb[j] = *(const bh8*)&Ks[(j * 16 + lr) * 136 + kcol[kc] + lg * 8];
#pragma unroll
            for (int j = 0; j < 4; ++j)
                sf[j] = __builtin_amdgcn_mfma_f32_16x16x32_bf16(qa[kc], kb[j], sf[j], 0, 0, 0);
        }
        __builtin_amdgcn_s_setprio(0);

        // per-lane local max only (no shuffles on the fast path)
        float lmx[4];
#pragma unroll
        for (int r = 0; r < 4; ++r)
            lmx[r] = fmaxf(fmaxf(sf[0][r], sf[1][r]), fmaxf(sf[2][r], sf[3][r]));
        bool grow = false;
#pragma unroll
        for (int r = 0; r < 4; ++r) grow = grow || (lmx[r] > m4[r] + 8.f);
        if (__any(grow)) {
            float mxr[4];
#pragma unroll
            for (int r = 0; r < 4; ++r) mxr[r] = lmx[r];
#pragma unroll
            for (int off = 1; off < 16; off <<= 1)
#pragma unroll
                for (int r = 0; r < 4; ++r)
                    mxr[r] = fmaxf(mxr[r], __shfl_xor(mxr[r], off));
#pragma unroll
            for (int r = 0; r < 4; ++r) {
                const float mn = fmaxf(m4[r], mxr[r]);
                const float corr = __expf(m4[r] - mn);
                m4[r] = mn;
                l4[r] *= corr;
#pragma unroll
                for (int j = 0; j < 4; ++j) o[j][r] *= corr;
            }
        }

#pragma unroll
        for (int j = 0; j < 4; ++j)
#pragma unroll
            for (int r = 0; r < 4; ++r)
                sf[j][r] = __expf(sf[j][r] - m4[r]);
#pragma unroll
        for (int r = 0; r < 4; ++r)
            l4[r] += (sf[0][r] + sf[1][r]) + (sf[2][r] + sf[3][r]);

        unsigned short* pw = Ps + wv * (16 * 72);
#pragma unroll
        for (int j = 0; j < 4; ++j)
#pragma unroll
            for (int r = 0; r < 4; ++r)
                pw[(lg * 4 + r) * 72 + j * 16 + lr] = f2bf_rne(sf[j][r]);

        __builtin_amdgcn_s_setprio(1);
#pragma unroll
        for (int kc = 0; kc < 2; ++kc) {
            bh8 pa = *(const bh8*)&pw[lr * 72 + kc * 32 + lg * 8];
            bh8 vb[4];
#pragma unroll
            for (int j = 0; j < 4; ++j)
                vb[j] = *(const bh8*)&Vs[(j * 16 + lr) * 72 + kc * 32 + lg * 8];
#pragma unroll
            for (int j = 0; j < 4; ++j)
                o[j] = __builtin_amdgcn_mfma_f32_16x16x32_bf16(pa, vb[j], o[j], 0, 0, 0);
        }
        __builtin_amdgcn_s_setprio(0);
    }

    // single deferred 16-lane l reduction
#pragma unroll
    for (int off = 1; off < 16; off <<= 1)
#pragma unroll
        for (int r = 0; r < 4; ++r)
            l4[r] += __shfl_xor(l4[r], off);

    float inv[4];
#pragma unroll
    for (int r = 0; r < 4; ++r) inv[r] = 1.f / l4[r];
    const int trow = b * SEQ + qb * 64 + wv * 16 + lg * 4;
#pragma unroll
    for (int r = 0; r < 4; ++r) {
        unsigned short* row = Ae2 + (size_t)(trow + r) * KAe;
#pragma unroll
        for (int j = 0; j < 4; ++j) {
            const float v = o[j][r] * inv[r];
            const unsigned short hi = f2bf_rne(v);
            const unsigned short lo = f2bf_rne(v - bf2f(hi));
            const int c = h * HD + j * 16 + lr;
            row[c] = hi; row[768 + c] = lo;
        }
    }
}

// ---------------------------------------------------------------------------
extern "C" void kernel_launch(void* const* d_in, const int* in_sizes, int n_in,
                              void* d_out, int out_size, void* d_ws, size_t ws_size,
                              hipStream_t stream)
{
    const float* x      = (const float*)d_in[0];
    const float* W_qkv  = (const float*)d_in[1];
    const float* b_qkv  = (const float*)d_in[2];
    const float* W_gate = (const float*)d_in[3];
    const float* b_gate = (const float*)d_in[4];
    const float* A      = (const float*)d_in[5];
    const float* B_lora = (const float*)d_in[6];
    const float* W_proj = (const float*)d_in[7];
    const float* b_proj = (const float*)d_in[8];
    float* out = (float*)d_out;

    // workspace (~57 MB). Ae2 (TTxKAe) aliases A2 (TTxKA) — disjoint lifetimes.
    unsigned short* A2  = (unsigned short*)d_ws;        // TT x KA
    unsigned short* B2  = A2 + (size_t)TT * KA;         // D3 x KB
    unsigned* Qp        = (unsigned*)(B2 + (size_t)D3 * KB);  // NBH x 512 x 64 u32
    unsigned* Kp        = Qp + (size_t)NBH * SEQ * HD;        // NBH x 512 x 64 u32
    unsigned short* Vt  = (unsigned short*)(Kp + (size_t)NBH * SEQ * HD); // NBH x 64 x 512
    unsigned short* Wpe = Vt + (size_t)NBH * HD * SEQ;  // D x KWp
    unsigned short* Ae2 = A2;                           // TT x KAe (attn output)

    // 1. prep: router (+x conversion from registers) + uniform W streams
    k_router<<<TT, 64, 0, stream>>>(x, W_gate, b_gate, A, A2);
    k_wconv<<<3456, 256, 0, stream>>>(W_qkv, W_proj, B_lora, B2, Wpe);

    // 2. QKV GEMM (logical K=2560 bf16x3+LoRA over dedup'd phys storage)
    //    128x96 tiles -> 24x32 = 768 blocks = exactly 3/CU
    {
        dim3 grid(D3 / 96, TT / 128);
        k_gemm_mfma<4, 3, 1, KA, KB><<<grid, 256, 0, stream>>>(
            A2, B2, b_qkv, nullptr, D3, KQ, Qp, Kp, Vt);
    }

    // 3. MFMA flash attention -> Ae2 (bh-locality swizzled grid)
    k_attn_mfma<<<NBH * 8, 256, 0, stream>>>(Qp, Kp, Vt, Ae2);

    // 4. output projection: 64x96 tiles -> 8x64 = 512 blocks = exactly 2/CU
    {
        dim3 grid(D / 96, TT / 64);
        k_gemm_mfma<2, 3, 0, KAe, KWp><<<grid, 256, 0, stream>>>(
            Ae2, Wpe, b_proj, out, D, KE, nullptr, nullptr, nullptr);
    }
}